// Round 2
// baseline (858.980 us; speedup 1.0000x reference)
//
#include <hip/hip_runtime.h>
#include <hip/hip_bf16.h>
#include <initializer_list>

typedef _Float16 half8 __attribute__((ext_vector_type(8)));
typedef float floatx4 __attribute__((ext_vector_type(4)));

#define MFMA16(a, b, c) __builtin_amdgcn_mfma_f32_16x16x32_f16((a), (b), (c), 0, 0, 0)

// async global->LDS, 16B per lane; LDS dest = wave-uniform base + lane*16
__device__ __forceinline__ void gload16(const void* g, void* l) {
    __builtin_amdgcn_global_load_lds((const __attribute__((address_space(1))) unsigned int*)g,
                                     (__attribute__((address_space(3))) unsigned int*)l,
                                     16, 0, 0);
}

// ---------------------------------------------------------------- LayerNorm
__global__ __launch_bounds__(256) void ln_kernel(const float* __restrict__ x,
                                                 const float* __restrict__ gamma,
                                                 const float* __restrict__ beta,
                                                 _Float16* __restrict__ xn) {
    int row = blockIdx.x;
    int tid = threadIdx.x;
    float2 v = ((const float2*)(x + (size_t)row * 512))[tid];

    __shared__ float red[4];
    __shared__ float mv[2];

    float s = v.x + v.y;
#pragma unroll
    for (int o = 32; o > 0; o >>= 1) s += __shfl_down(s, o);
    if ((tid & 63) == 0) red[tid >> 6] = s;
    __syncthreads();
    if (tid == 0) mv[0] = (red[0] + red[1] + red[2] + red[3]) * (1.f / 512.f);
    __syncthreads();
    float mean = mv[0];

    float dx = v.x - mean, dy = v.y - mean;
    float sq = dx * dx + dy * dy;
#pragma unroll
    for (int o = 32; o > 0; o >>= 1) sq += __shfl_xor(sq, o);
    __syncthreads();
    if ((tid & 63) == 0) red[tid >> 6] = sq;
    __syncthreads();
    if (tid == 0) mv[1] = rsqrtf((red[0] + red[1] + red[2] + red[3]) * (1.f / 512.f) + 1e-5f);
    __syncthreads();
    float rstd = mv[1];

    float g0 = gamma[tid * 2], g1 = gamma[tid * 2 + 1];
    float b0 = beta[tid * 2], b1 = beta[tid * 2 + 1];
    union { _Float16 h[2]; unsigned int u; } pk;
    pk.h[0] = (_Float16)(dx * rstd * g0 + b0);
    pk.h[1] = (_Float16)(dy * rstd * g1 + b1);
    ((unsigned int*)(xn + (size_t)row * 512))[tid] = pk.u;
}

// ------------------------------------------------- tiled transpose + cast fp32->fp16
// in: [R][C] f32 row-major; out: [C][R] f16. grid (C/32, R/32), 256 threads (32x8).
__global__ __launch_bounds__(256) void transpose_cast(const float* __restrict__ in,
                                                      _Float16* __restrict__ out,
                                                      int R, int C) {
    __shared__ float t[32][33];
    int c0 = blockIdx.x * 32, r0 = blockIdx.y * 32;
    int tx = threadIdx.x & 31, ty = threadIdx.x >> 5;
#pragma unroll
    for (int j = 0; j < 4; ++j)
        t[ty + j * 8][tx] = in[(size_t)(r0 + ty + j * 8) * C + c0 + tx];
    __syncthreads();
#pragma unroll
    for (int j = 0; j < 4; ++j)
        out[(size_t)(c0 + ty + j * 8) * R + r0 + tx] = (_Float16)t[tx][ty + j * 8];
}

// ---------------------------------------------------------------- GEMM (B^T)
// C[M,N] = A[M,K] @ Bt[N,K]^T + bias[N]
// Staging via global_load_lds (16B/lane), linear LDS [128][32] halves with
// both-sides XOR swizzle: source col-block pre-swizzled, reads XOR'd -> 2-way (free).
// OUTMODE 1: fp32 final store. OUTMODE 2: QKV-split writer (Q|K compact + V transposed).
template <int OUTMODE>
__global__ __launch_bounds__(256) void gemm_bt(const _Float16* __restrict__ A,
                                               const _Float16* __restrict__ Bt,
                                               const float* __restrict__ bias,
                                               void* __restrict__ Cout,
                                               _Float16* __restrict__ Vt,
                                               int M, int N, int K) {
    __shared__ __align__(16) _Float16 Asb[128 * 32];
    __shared__ __align__(16) _Float16 Bsb[128 * 32];

    int m0 = blockIdx.x * 128;
    int n0 = blockIdx.y * 128;
    int tid = threadIdx.x;
    int w = tid >> 6, lane = tid & 63, lrow = lane & 15, quad = lane >> 4;
    int wm = (w >> 1) * 64, wn = (w & 1) * 64;

    // staging geometry: wave w, issue it covers rows it*64 + w*16 + (lane>>2);
    // lane writes linear LDS slot (row, lane&3); global col-block = (lane&3) ^ ((lane>>3)&3)
    int srow = lane >> 2;
    int scb = (lane & 3) ^ ((lane >> 3) & 3);
    const _Float16* Abase = A + (size_t)(m0 + w * 16 + srow) * K + scb * 8;
    const _Float16* Bbase = Bt + (size_t)(n0 + w * 16 + srow) * K + scb * 8;
    char* AldsB = (char*)Asb + w * 1024;
    char* BldsB = (char*)Bsb + w * 1024;
    const size_t rowskip = (size_t)64 * K;

    int swz = (lrow >> 1) & 3;  // read-side XOR

    floatx4 acc[4][4];
#pragma unroll
    for (int i = 0; i < 4; ++i)
#pragma unroll
        for (int j = 0; j < 4; ++j) acc[i][j] = (floatx4){0.f, 0.f, 0.f, 0.f};

    for (int k0 = 0; k0 < K; k0 += 32) {
        __syncthreads();
        gload16(Abase + k0, AldsB);
        gload16(Abase + rowskip + k0, AldsB + 4096);
        gload16(Bbase + k0, BldsB);
        gload16(Bbase + rowskip + k0, BldsB + 4096);
        __syncthreads();

        half8 af[4], bf[4];
#pragma unroll
        for (int i = 0; i < 4; ++i) {
            int r = wm + i * 16 + lrow;
            af[i] = *(const half8*)&Asb[r * 32 + (quad ^ swz) * 8];
        }
#pragma unroll
        for (int j = 0; j < 4; ++j) {
            int r = wn + j * 16 + lrow;
            bf[j] = *(const half8*)&Bsb[r * 32 + (quad ^ swz) * 8];
        }
#pragma unroll
        for (int i = 0; i < 4; ++i)
#pragma unroll
            for (int j = 0; j < 4; ++j)
                acc[i][j] = MFMA16(af[i], bf[j], acc[i][j]);
    }

    int hh = blockIdx.y / 3;
    int part = blockIdx.y - hh * 3;

#pragma unroll
    for (int i = 0; i < 4; ++i)
#pragma unroll
        for (int j = 0; j < 4; ++j) {
            int colg = n0 + wn + j * 16 + lrow;
            int coll = wn + j * 16 + lrow;
            float bv = bias[colg];
#pragma unroll
            for (int r = 0; r < 4; ++r) {
                int rowg = m0 + wm + i * 16 + quad * 4 + r;
                float v = acc[i][j][r] + bv;
                if (OUTMODE == 1) {
                    ((float*)Cout)[(size_t)rowg * N + colg] = v;
                } else {
                    if (part == 0) {
                        ((_Float16*)Cout)[(size_t)rowg * 1024 + hh * 128 + coll] = (_Float16)v;
                    } else {
                        int d = (part - 1) * 128 + coll;
                        int b_rel = rowg >> 10;
                        int n = rowg & 1023;
                        Vt[(((size_t)b_rel * 8 + hh) * 256 + d) * 1024 + n] = (_Float16)v;
                    }
                }
            }
        }
}

// ---------------------------------------------------------------- attention
// qk: [b*n][h*128 (q64|k64)]; vt: [b][h][d=256][n=1024] fp16.
// Swapped QK^T, in-register P, exp2-domain softmax, V_t stride 40 (2-way, aligned).
__global__ __launch_bounds__(256) void attn_kernel(const _Float16* __restrict__ qk,
                                                   const _Float16* __restrict__ vt,
                                                   const float* __restrict__ biases,
                                                   _Float16* __restrict__ out) {
    int h  = blockIdx.x & 7;
    int qt = (blockIdx.x >> 3) | (blockIdx.y << 1);
    int b  = blockIdx.z;

    int tid = threadIdx.x;
    int w = tid >> 6, lane = tid & 63, lrow = lane & 15, quad = lane >> 4;

    __shared__ float bias_lds[1024];
    __shared__ __align__(16) _Float16 K_lds[32 * 72];  // [key][kd] stride 72
    __shared__ __align__(16) _Float16 V_t[256 * 40];   // [d][k-slot] stride 40: 2-way, 16B-aligned

    const float LOG2E = 1.44269504f;
    for (int i = tid; i < 1024; i += 256) bias_lds[i] = biases[h * 1024 + i] * LOG2E;

    int qrow = qt * 64 + w * 16 + lrow;
    const _Float16* qbase = qk + ((size_t)(b * 1024 + qrow)) * 1024 + h * 128;
    half8 aq0 = *(const half8*)(qbase + quad * 8);
    half8 aq1 = *(const half8*)(qbase + 32 + quad * 8);

    int key_l = tid >> 3, kd8 = (tid & 7) * 8;
    const _Float16* ksrc = qk + ((size_t)(b * 1024 + key_l)) * 1024 + h * 128 + 64 + kd8;
    int cc = tid & 3;
    const _Float16* vsrc0 = vt + ((size_t)((b * 8 + h) * 256 + (tid >> 2))) * 1024 + cc * 4;

    int qr = qrow >> 5, qc = qrow & 31;
    int bcol0[4], bcol1[4];
#pragma unroll
    for (int r = 0; r < 4; ++r) {
        bcol0[r] = abs(qc - (quad * 4 + r));
        bcol1[r] = abs(qc - (16 + quad * 4 + r));
    }

    float m_r = -1e30f, l_r = 0.f;
    floatx4 od[16];
#pragma unroll
    for (int dt = 0; dt < 16; ++dt) od[dt] = (floatx4){0.f, 0.f, 0.f, 0.f};

    uint4 kreg;
    uint2 vA[4], vB[4];

    kreg = *(const uint4*)ksrc;
#pragma unroll
    for (int it = 0; it < 4; ++it) {
        const _Float16* p = vsrc0 + (size_t)it * 64 * 1024;
        vA[it] = *(const uint2*)p;
        vB[it] = *(const uint2*)(p + 16);
    }

    const float SCL = 0.125f * LOG2E;

    for (int kt = 0; kt < 32; ++kt) {
        *(uint4*)&K_lds[key_l * 72 + kd8] = kreg;
#pragma unroll
        for (int it = 0; it < 4; ++it) {
            uint4 v;
            v.x = vA[it].x; v.y = vA[it].y; v.z = vB[it].x; v.w = vB[it].y;
            *(uint4*)&V_t[((tid >> 2) + it * 64) * 40 + cc * 8] = v;
        }
        __syncthreads();

        if (kt < 31) {
            kreg = *(const uint4*)(ksrc + (size_t)(kt + 1) * 32 * 1024);
            const _Float16* vp = vsrc0 + (size_t)(kt + 1) * 32;
#pragma unroll
            for (int it = 0; it < 4; ++it) {
                const _Float16* p = vp + (size_t)it * 64 * 1024;
                vA[it] = *(const uint2*)p;
                vB[it] = *(const uint2*)(p + 16);
            }
        }

        floatx4 sc0 = (floatx4){0.f, 0.f, 0.f, 0.f}, sc1 = sc0;
        {
            half8 kf;
            kf = *(const half8*)&K_lds[lrow * 72 + quad * 8];              sc0 = MFMA16(kf, aq0, sc0);
            kf = *(const half8*)&K_lds[lrow * 72 + 32 + quad * 8];         sc0 = MFMA16(kf, aq1, sc0);
            kf = *(const half8*)&K_lds[(16 + lrow) * 72 + quad * 8];       sc1 = MFMA16(kf, aq0, sc1);
            kf = *(const half8*)&K_lds[(16 + lrow) * 72 + 32 + quad * 8];  sc1 = MFMA16(kf, aq1, sc1);
        }

        int rowoff = abs(qr - kt) << 5;
        float s0[4], s1[4];
#pragma unroll
        for (int r = 0; r < 4; ++r) {
            s0[r] = sc0[r] * SCL + bias_lds[rowoff + bcol0[r]];
            s1[r] = sc1[r] * SCL + bias_lds[rowoff + bcol1[r]];
        }

        float pmax = fmaxf(fmaxf(fmaxf(s0[0], s0[1]), fmaxf(s0[2], s0[3])),
                           fmaxf(fmaxf(s1[0], s1[1]), fmaxf(s1[2], s1[3])));
        pmax = fmaxf(pmax, __shfl_xor(pmax, 16));
        pmax = fmaxf(pmax, __shfl_xor(pmax, 32));

        if (!__all(pmax - m_r <= 8.f)) {
            float mnew = fmaxf(m_r, pmax);
            float alpha = exp2f(m_r - mnew);
            m_r = mnew;
            l_r *= alpha;
            float a4[4];
#pragma unroll
            for (int r = 0; r < 4; ++r) a4[r] = __shfl(alpha, quad * 4 + r, 16);
#pragma unroll
            for (int dt = 0; dt < 16; ++dt)
#pragma unroll
                for (int r = 0; r < 4; ++r) od[dt][r] *= a4[r];
        }

        float p0[4], p1[4], rs = 0.f;
#pragma unroll
        for (int r = 0; r < 4; ++r) { p0[r] = exp2f(s0[r] - m_r); rs += p0[r]; }
#pragma unroll
        for (int r = 0; r < 4; ++r) { p1[r] = exp2f(s1[r] - m_r); rs += p1[r]; }
        rs += __shfl_xor(rs, 16);
        rs += __shfl_xor(rs, 32);
        l_r += rs;

        union { unsigned int u[4]; half8 v; } pa;
        pa.u[0] = __builtin_bit_cast(unsigned int, __builtin_amdgcn_cvt_pkrtz(p0[0], p0[1]));
        pa.u[1] = __builtin_bit_cast(unsigned int, __builtin_amdgcn_cvt_pkrtz(p0[2], p0[3]));
        pa.u[2] = __builtin_bit_cast(unsigned int, __builtin_amdgcn_cvt_pkrtz(p1[0], p1[1]));
        pa.u[3] = __builtin_bit_cast(unsigned int, __builtin_amdgcn_cvt_pkrtz(p1[2], p1[3]));

#pragma unroll
        for (int dt = 0; dt < 16; ++dt) {
            half8 bv = *(const half8*)&V_t[(dt * 16 + lrow) * 40 + quad * 8];
            od[dt] = MFMA16(pa.v, bv, od[dt]);
        }
        __syncthreads();
    }

#pragma unroll
    for (int r = 0; r < 4; ++r) {
        float lq = __shfl(l_r, quad * 4 + r, 16);
        float inv = 1.f / lq;
        int qg = qt * 64 + w * 16 + quad * 4 + r;
        _Float16* orow = out + ((size_t)(b * 1024 + qg)) * 2048 + h * 256;
#pragma unroll
        for (int dt = 0; dt < 16; ++dt)
            orow[dt * 16 + lrow] = (_Float16)(od[dt][r] * inv);
    }
}

// ---------------------------------------------------------------- launch
extern "C" void kernel_launch(void* const* d_in, const int* in_sizes, int n_in,
                              void* d_out, int out_size, void* d_ws, size_t ws_size,
                              hipStream_t stream) {
    const float* x      = (const float*)d_in[0];
    const float* gamma  = (const float*)d_in[1];
    const float* beta   = (const float*)d_in[2];
    const float* qkv_w  = (const float*)d_in[3];
    const float* qkv_b  = (const float*)d_in[4];
    const float* proj_w = (const float*)d_in[5];
    const float* proj_b = (const float*)d_in[6];
    const float* biases = (const float*)d_in[7];

    float* out = (float*)d_out;

    _Float16* ws      = (_Float16*)d_ws;
    _Float16* qkv_wt  = ws;                                   //  512*3072
    _Float16* proj_wt = qkv_wt + (size_t)512 * 3072;          // 2048*512
    _Float16* xn      = proj_wt + (size_t)2048 * 512;         // 32768*512
    _Float16* chunk0  = xn + (size_t)32768 * 512;

    const size_t FIXED_HALVES = (size_t)512 * 3072 + (size_t)2048 * 512 + (size_t)32768 * 512;
    int CB = 0;
    for (int cb : {16, 8, 4, 2, 1}) {
        size_t halves = FIXED_HALVES + (size_t)cb * 1024 * (1024 + 2048 + 2048);
        if (halves * sizeof(_Float16) <= ws_size) { CB = cb; break; }
    }
    if (CB == 0) return;
    _Float16* qk_c  = chunk0;                                 // CB*1024*1024
    _Float16* vt_c  = qk_c + (size_t)CB * 1024 * 1024;        // CB*1024*2048
    _Float16* att_c = vt_c + (size_t)CB * 1024 * 2048;        // CB*1024*2048

    transpose_cast<<<dim3(3072 / 32, 512 / 32), 256, 0, stream>>>(qkv_w, qkv_wt, 512, 3072);
    transpose_cast<<<dim3(512 / 32, 2048 / 32), 256, 0, stream>>>(proj_w, proj_wt, 2048, 512);
    ln_kernel<<<32768, 256, 0, stream>>>(x, gamma, beta, xn);

    const int MC = CB * 1024;
    for (int c = 0; c < 32 / CB; ++c) {
        const _Float16* xn_c = xn + (size_t)c * MC * 512;
        gemm_bt<2><<<dim3(MC / 128, 24), 256, 0, stream>>>(xn_c, qkv_wt, qkv_b,
                                                           (void*)qk_c, vt_c, MC, 3072, 512);
        attn_kernel<<<dim3(16, 8, CB), 256, 0, stream>>>(qk_c, vt_c, biases, att_c);
        float* out_c = out + (size_t)c * MC * 512;
        gemm_bt<1><<<dim3(MC / 128, 4), 256, 0, stream>>>(att_c, proj_wt, proj_b,
                                                          (void*)out_c, nullptr, MC, 512, 2048);
    }
}

// Round 3
// 791.578 us; speedup vs baseline: 1.0851x; 1.0851x over previous
//
#include <hip/hip_runtime.h>
#include <hip/hip_bf16.h>
#include <initializer_list>

typedef _Float16 half8 __attribute__((ext_vector_type(8)));
typedef float floatx4 __attribute__((ext_vector_type(4)));

#define MFMA16(a, b, c) __builtin_amdgcn_mfma_f32_16x16x32_f16((a), (b), (c), 0, 0, 0)

// async global->LDS, 16B per lane; LDS dest = wave-uniform base + lane*16
__device__ __forceinline__ void gload16(const void* g, void* l) {
    __builtin_amdgcn_global_load_lds((const __attribute__((address_space(1))) unsigned int*)g,
                                     (__attribute__((address_space(3))) unsigned int*)l,
                                     16, 0, 0);
}

// ---------------------------------------------------------------- LayerNorm
__global__ __launch_bounds__(256) void ln_kernel(const float* __restrict__ x,
                                                 const float* __restrict__ gamma,
                                                 const float* __restrict__ beta,
                                                 _Float16* __restrict__ xn) {
    int row = blockIdx.x;
    int tid = threadIdx.x;
    float2 v = ((const float2*)(x + (size_t)row * 512))[tid];

    __shared__ float red[4];
    __shared__ float mv[2];

    float s = v.x + v.y;
#pragma unroll
    for (int o = 32; o > 0; o >>= 1) s += __shfl_down(s, o);
    if ((tid & 63) == 0) red[tid >> 6] = s;
    __syncthreads();
    if (tid == 0) mv[0] = (red[0] + red[1] + red[2] + red[3]) * (1.f / 512.f);
    __syncthreads();
    float mean = mv[0];

    float dx = v.x - mean, dy = v.y - mean;
    float sq = dx * dx + dy * dy;
#pragma unroll
    for (int o = 32; o > 0; o >>= 1) sq += __shfl_xor(sq, o);
    __syncthreads();
    if ((tid & 63) == 0) red[tid >> 6] = sq;
    __syncthreads();
    if (tid == 0) mv[1] = rsqrtf((red[0] + red[1] + red[2] + red[3]) * (1.f / 512.f) + 1e-5f);
    __syncthreads();
    float rstd = mv[1];

    float g0 = gamma[tid * 2], g1 = gamma[tid * 2 + 1];
    float b0 = beta[tid * 2], b1 = beta[tid * 2 + 1];
    union { _Float16 h[2]; unsigned int u; } pk;
    pk.h[0] = (_Float16)(dx * rstd * g0 + b0);
    pk.h[1] = (_Float16)(dy * rstd * g1 + b1);
    ((unsigned int*)(xn + (size_t)row * 512))[tid] = pk.u;
}

// ------------------------------------------------- tiled transpose + cast fp32->fp16
__global__ __launch_bounds__(256) void transpose_cast(const float* __restrict__ in,
                                                      _Float16* __restrict__ out,
                                                      int R, int C) {
    __shared__ float t[32][33];
    int c0 = blockIdx.x * 32, r0 = blockIdx.y * 32;
    int tx = threadIdx.x & 31, ty = threadIdx.x >> 5;
#pragma unroll
    for (int j = 0; j < 4; ++j)
        t[ty + j * 8][tx] = in[(size_t)(r0 + ty + j * 8) * C + c0 + tx];
    __syncthreads();
#pragma unroll
    for (int j = 0; j < 4; ++j)
        out[(size_t)(c0 + ty + j * 8) * R + r0 + tx] = (_Float16)t[tx][ty + j * 8];
}

// ---------------------------------------------------------------- GEMM (B^T)
// C[M,N] = A[M,K] @ Bt[N,K]^T + bias[N]
// Staging via global_load_lds (16B/lane), linear LDS [128][32] halves with
// both-sides XOR swizzle. OUTMODE 1: fp32 final store. OUTMODE 2: QKV-split
// writer; V col-blocks use SWAPPED-OPERAND MFMA so the output fragment is
// transposed in-registers -> coalesced 32B-segment stores to Vt[d][n].
template <int OUTMODE>
__global__ __launch_bounds__(256) void gemm_bt(const _Float16* __restrict__ A,
                                               const _Float16* __restrict__ Bt,
                                               const float* __restrict__ bias,
                                               void* __restrict__ Cout,
                                               _Float16* __restrict__ Vt,
                                               int M, int N, int K) {
    __shared__ __align__(16) _Float16 Asb[128 * 32];
    __shared__ __align__(16) _Float16 Bsb[128 * 32];

    int m0 = blockIdx.x * 128;
    int n0 = blockIdx.y * 128;
    int tid = threadIdx.x;
    int w = tid >> 6, lane = tid & 63, lrow = lane & 15, quad = lane >> 4;
    int wm = (w >> 1) * 64, wn = (w & 1) * 64;

    int hh = 0, part = 0;
    bool sw = false;
    if (OUTMODE == 2) {
        hh = blockIdx.y / 3;
        part = blockIdx.y - hh * 3;
        sw = (part != 0);
    }

    int srow = lane >> 2;
    int scb = (lane & 3) ^ ((lane >> 3) & 3);
    const _Float16* Abase = A + (size_t)(m0 + w * 16 + srow) * K + scb * 8;
    const _Float16* Bbase = Bt + (size_t)(n0 + w * 16 + srow) * K + scb * 8;
    char* AldsB = (char*)Asb + w * 1024;
    char* BldsB = (char*)Bsb + w * 1024;
    const size_t rowskip = (size_t)64 * K;

    int swz = (lrow >> 1) & 3;

    floatx4 acc[4][4];
#pragma unroll
    for (int i = 0; i < 4; ++i)
#pragma unroll
        for (int j = 0; j < 4; ++j) acc[i][j] = (floatx4){0.f, 0.f, 0.f, 0.f};

    for (int k0 = 0; k0 < K; k0 += 32) {
        __syncthreads();
        gload16(Abase + k0, AldsB);
        gload16(Abase + rowskip + k0, AldsB + 4096);
        gload16(Bbase + k0, BldsB);
        gload16(Bbase + rowskip + k0, BldsB + 4096);
        __syncthreads();

        half8 af[4], bf[4];
#pragma unroll
        for (int i = 0; i < 4; ++i) {
            int r = wm + i * 16 + lrow;
            af[i] = *(const half8*)&Asb[r * 32 + (quad ^ swz) * 8];
        }
#pragma unroll
        for (int j = 0; j < 4; ++j) {
            int r = wn + j * 16 + lrow;
            bf[j] = *(const half8*)&Bsb[r * 32 + (quad ^ swz) * 8];
        }
        if (OUTMODE == 2 && sw) {
#pragma unroll
            for (int i = 0; i < 4; ++i)
#pragma unroll
                for (int j = 0; j < 4; ++j)
                    acc[i][j] = MFMA16(bf[j], af[i], acc[i][j]);
        } else {
#pragma unroll
            for (int i = 0; i < 4; ++i)
#pragma unroll
                for (int j = 0; j < 4; ++j)
                    acc[i][j] = MFMA16(af[i], bf[j], acc[i][j]);
        }
    }

    if (OUTMODE == 2 && sw) {
        // transposed fragment: lane lrow <-> token (contiguous), quad*4+r <-> d
        int b_rel = m0 >> 10;
        int tok0 = (m0 & 1023) + wm;
        _Float16* vbase = Vt + (((size_t)b_rel * 8 + hh) * 256 + (part - 1) * 128) * 1024;
#pragma unroll
        for (int j = 0; j < 4; ++j)
#pragma unroll
            for (int r = 0; r < 4; ++r) {
                int d = wn + j * 16 + quad * 4 + r;
                float bv = bias[n0 + d];
                _Float16* vrow = vbase + (size_t)d * 1024 + tok0;
#pragma unroll
                for (int i = 0; i < 4; ++i)
                    vrow[i * 16 + lrow] = (_Float16)(acc[i][j][r] + bv);
            }
        return;
    }

#pragma unroll
    for (int i = 0; i < 4; ++i)
#pragma unroll
        for (int j = 0; j < 4; ++j) {
            int colg = n0 + wn + j * 16 + lrow;
            int coll = wn + j * 16 + lrow;
            float bv = bias[colg];
#pragma unroll
            for (int r = 0; r < 4; ++r) {
                int rowg = m0 + wm + i * 16 + quad * 4 + r;
                float v = acc[i][j][r] + bv;
                if (OUTMODE == 1) {
                    ((float*)Cout)[(size_t)rowg * N + colg] = v;
                } else {
                    ((_Float16*)Cout)[(size_t)rowg * 1024 + hh * 128 + coll] = (_Float16)v;
                }
            }
        }
}

// ---------------------------------------------------------------- attention
// (round-1 form: V_t stride 32, __expf softmax, manual P pack — measured 195 us)
__global__ __launch_bounds__(256) void attn_kernel(const _Float16* __restrict__ qk,
                                                   const _Float16* __restrict__ vt,
                                                   const float* __restrict__ biases,
                                                   _Float16* __restrict__ out) {
    int h  = blockIdx.x & 7;
    int qt = (blockIdx.x >> 3) | (blockIdx.y << 1);
    int b  = blockIdx.z;

    int tid = threadIdx.x;
    int w = tid >> 6, lane = tid & 63, lrow = lane & 15, quad = lane >> 4;

    __shared__ float bias_lds[1024];
    __shared__ __align__(16) _Float16 K_lds[32 * 72];
    __shared__ __align__(16) _Float16 V_t[256 * 32];

    for (int i = tid; i < 1024; i += 256) bias_lds[i] = biases[h * 1024 + i];

    int qrow = qt * 64 + w * 16 + lrow;
    const _Float16* qbase = qk + ((size_t)(b * 1024 + qrow)) * 1024 + h * 128;
    half8 aq0 = *(const half8*)(qbase + quad * 8);
    half8 aq1 = *(const half8*)(qbase + 32 + quad * 8);

    int key_l = tid >> 3, kd8 = (tid & 7) * 8;
    const _Float16* ksrc = qk + ((size_t)(b * 1024 + key_l)) * 1024 + h * 128 + 64 + kd8;
    int cc = tid & 3;
    const _Float16* vsrc0 = vt + ((size_t)((b * 8 + h) * 256 + (tid >> 2))) * 1024 + cc * 4;

    int qr = qrow >> 5, qc = qrow & 31;
    int bcol0[4], bcol1[4];
#pragma unroll
    for (int r = 0; r < 4; ++r) {
        bcol0[r] = abs(qc - (quad * 4 + r));
        bcol1[r] = abs(qc - (16 + quad * 4 + r));
    }

    float m_r = -1e30f, l_r = 0.f;
    floatx4 od[16];
#pragma unroll
    for (int dt = 0; dt < 16; ++dt) od[dt] = (floatx4){0.f, 0.f, 0.f, 0.f};

    uint4 kreg;
    uint2 vA[4], vB[4];

    kreg = *(const uint4*)ksrc;
#pragma unroll
    for (int it = 0; it < 4; ++it) {
        const _Float16* p = vsrc0 + (size_t)it * 64 * 1024;
        vA[it] = *(const uint2*)p;
        vB[it] = *(const uint2*)(p + 16);
    }

    for (int kt = 0; kt < 32; ++kt) {
        *(uint4*)&K_lds[key_l * 72 + kd8] = kreg;
#pragma unroll
        for (int it = 0; it < 4; ++it) {
            uint4 v;
            v.x = vA[it].x; v.y = vA[it].y; v.z = vB[it].x; v.w = vB[it].y;
            *(uint4*)&V_t[((tid >> 2) + it * 64) * 32 + cc * 8] = v;
        }
        __syncthreads();

        if (kt < 31) {
            kreg = *(const uint4*)(ksrc + (size_t)(kt + 1) * 32 * 1024);
            const _Float16* vp = vsrc0 + (size_t)(kt + 1) * 32;
#pragma unroll
            for (int it = 0; it < 4; ++it) {
                const _Float16* p = vp + (size_t)it * 64 * 1024;
                vA[it] = *(const uint2*)p;
                vB[it] = *(const uint2*)(p + 16);
            }
        }

        floatx4 sc0 = (floatx4){0.f, 0.f, 0.f, 0.f}, sc1 = sc0;
        {
            half8 kf;
            kf = *(const half8*)&K_lds[lrow * 72 + quad * 8];              sc0 = MFMA16(kf, aq0, sc0);
            kf = *(const half8*)&K_lds[lrow * 72 + 32 + quad * 8];         sc0 = MFMA16(kf, aq1, sc0);
            kf = *(const half8*)&K_lds[(16 + lrow) * 72 + quad * 8];       sc1 = MFMA16(kf, aq0, sc1);
            kf = *(const half8*)&K_lds[(16 + lrow) * 72 + 32 + quad * 8];  sc1 = MFMA16(kf, aq1, sc1);
        }

        int rowoff = abs(qr - kt) << 5;
        float s0[4], s1[4];
#pragma unroll
        for (int r = 0; r < 4; ++r) {
            s0[r] = sc0[r] * 0.125f + bias_lds[rowoff + bcol0[r]];
            s1[r] = sc1[r] * 0.125f + bias_lds[rowoff + bcol1[r]];
        }

        float pmax = fmaxf(fmaxf(fmaxf(s0[0], s0[1]), fmaxf(s0[2], s0[3])),
                           fmaxf(fmaxf(s1[0], s1[1]), fmaxf(s1[2], s1[3])));
        pmax = fmaxf(pmax, __shfl_xor(pmax, 16));
        pmax = fmaxf(pmax, __shfl_xor(pmax, 32));

        if (!__all(pmax - m_r <= 8.f)) {
            float mnew = fmaxf(m_r, pmax);
            float alpha = __expf(m_r - mnew);
            m_r = mnew;
            l_r *= alpha;
            float a4[4];
#pragma unroll
            for (int r = 0; r < 4; ++r) a4[r] = __shfl(alpha, quad * 4 + r, 16);
#pragma unroll
            for (int dt = 0; dt < 16; ++dt)
#pragma unroll
                for (int r = 0; r < 4; ++r) od[dt][r] *= a4[r];
        }

        float p0[4], p1[4], rs = 0.f;
#pragma unroll
        for (int r = 0; r < 4; ++r) { p0[r] = __expf(s0[r] - m_r); rs += p0[r]; }
#pragma unroll
        for (int r = 0; r < 4; ++r) { p1[r] = __expf(s1[r] - m_r); rs += p1[r]; }
        rs += __shfl_xor(rs, 16);
        rs += __shfl_xor(rs, 32);
        l_r += rs;

        union H8 { _Float16 h[8]; half8 v; } pa;
#pragma unroll
        for (int r = 0; r < 4; ++r) { pa.h[r] = (_Float16)p0[r]; pa.h[4 + r] = (_Float16)p1[r]; }

#pragma unroll
        for (int dt = 0; dt < 16; ++dt) {
            half8 bv = *(const half8*)&V_t[(dt * 16 + lrow) * 32 + quad * 8];
            od[dt] = MFMA16(pa.v, bv, od[dt]);
        }
        __syncthreads();
    }

#pragma unroll
    for (int r = 0; r < 4; ++r) {
        float lq = __shfl(l_r, quad * 4 + r, 16);
        float inv = 1.f / lq;
        int qg = qt * 64 + w * 16 + quad * 4 + r;
        _Float16* orow = out + ((size_t)(b * 1024 + qg)) * 2048 + h * 256;
#pragma unroll
        for (int dt = 0; dt < 16; ++dt)
            orow[dt * 16 + lrow] = (_Float16)(od[dt][r] * inv);
    }
}

// ---------------------------------------------------------------- launch
extern "C" void kernel_launch(void* const* d_in, const int* in_sizes, int n_in,
                              void* d_out, int out_size, void* d_ws, size_t ws_size,
                              hipStream_t stream) {
    const float* x      = (const float*)d_in[0];
    const float* gamma  = (const float*)d_in[1];
    const float* beta   = (const float*)d_in[2];
    const float* qkv_w  = (const float*)d_in[3];
    const float* qkv_b  = (const float*)d_in[4];
    const float* proj_w = (const float*)d_in[5];
    const float* proj_b = (const float*)d_in[6];
    const float* biases = (const float*)d_in[7];

    float* out = (float*)d_out;

    _Float16* ws      = (_Float16*)d_ws;
    _Float16* qkv_wt  = ws;                                   //  512*3072
    _Float16* proj_wt = qkv_wt + (size_t)512 * 3072;          // 2048*512
    _Float16* xn      = proj_wt + (size_t)2048 * 512;         // 32768*512
    _Float16* chunk0  = xn + (size_t)32768 * 512;

    const size_t FIXED_HALVES = (size_t)512 * 3072 + (size_t)2048 * 512 + (size_t)32768 * 512;
    int CB = 0;
    for (int cb : {16, 8, 4, 2, 1}) {
        size_t halves = FIXED_HALVES + (size_t)cb * 1024 * (1024 + 2048 + 2048);
        if (halves * sizeof(_Float16) <= ws_size) { CB = cb; break; }
    }
    if (CB == 0) return;
    _Float16* qk_c  = chunk0;                                 // CB*1024*1024
    _Float16* vt_c  = qk_c + (size_t)CB * 1024 * 1024;        // CB*1024*2048
    _Float16* att_c = vt_c + (size_t)CB * 1024 * 2048;        // CB*1024*2048

    transpose_cast<<<dim3(3072 / 32, 512 / 32), 256, 0, stream>>>(qkv_w, qkv_wt, 512, 3072);
    transpose_cast<<<dim3(512 / 32, 2048 / 32), 256, 0, stream>>>(proj_w, proj_wt, 2048, 512);
    ln_kernel<<<32768, 256, 0, stream>>>(x, gamma, beta, xn);

    const int MC = CB * 1024;
    for (int c = 0; c < 32 / CB; ++c) {
        const _Float16* xn_c = xn + (size_t)c * MC * 512;
        gemm_bt<2><<<dim3(MC / 128, 24), 256, 0, stream>>>(xn_c, qkv_wt, qkv_b,
                                                           (void*)qk_c, vt_c, MC, 3072, 512);
        attn_kernel<<<dim3(16, 8, CB), 256, 0, stream>>>(qk_c, vt_c, biases, att_c);
        float* out_c = out + (size_t)c * MC * 512;
        gemm_bt<1><<<dim3(MC / 128, 4), 256, 0, stream>>>(att_c, proj_wt, proj_b,
                                                          (void*)out_c, nullptr, MC, 512, 2048);
    }
}